// Round 6
// baseline (326.217 us; speedup 1.0000x reference)
//
#include <hip/hip_runtime.h>
#include <math.h>

#define IMG_H 1024
#define IMG_W 1024
#define IMG_B 8
#define TPB 256                    // 256 thr * 4 px = one full row
#define RB 16                      // output rows per band
#define BANDS (IMG_H / RB)         // 64
#define NBLK (IMG_B * BANDS)       // 512 blocks = 2/CU

__device__ __forceinline__ float sig2(float x) {   // sigmoid(2x) == sigmoid(x/EPS)
    return 1.0f / (1.0f + __expf(-2.0f * x));
}

// ---------------------------------------------------------------------------
// Barrier-free depth-2 fused kernel. Thread owns px [x0, x0+3]; computes the
// full 2-iteration pipeline on a shrinking halo window [x0-2 .. x0+5] held in
// registers. Local index i in [0..7] maps to global px x0-2+i.
// Per row y (sweeping ylo..yend, all recurrences in registers):
//   A: p0/p1 of q_i[y]          (i 0..7)
//   B: u_i[y] = sig2(o - Tq_i)  (i 1..7)
//   C: q'[y-1] + its p0'/p1'    (i 1..6)
//   D: u'[y-1] = sig2(o - Tq')  (i 2..6)
//   E: q''[y-2] -> global       (i 2..5)
// No LDS, no __syncthreads.
// ---------------------------------------------------------------------------
__global__ __launch_bounds__(TPB, 2) void k_fused2(const float* __restrict__ qin,
                                                   const float* __restrict__ vf,
                                                   const float* __restrict__ o,
                                                   float* __restrict__ qout) {
    const int img  = blockIdx.x / BANDS;
    const int r0   = (blockIdx.x % BANDS) * RB;
    const int x0   = threadIdx.x * 4;
    const bool topb = (r0 == 0);
    const bool lft  = (x0 == 0);
    const bool rgt  = (x0 == IMG_W - 4);
    const size_t ibase = (size_t)img * IMG_H * IMG_W;

    const int ylo   = topb ? 0 : r0 - 2;
    const int yend  = r0 + RB + 1;
    const int qp_lo = topb ? 0 : r0 - 1;       // first row where q' is real

    // carried row-recurrence state
    float p1A[8];  // p1 of q_i at row y-1
    float uA[8];   // u_i at row y-1
    float qAr[8];  // q_i at row y-1
    float v0B[8], v1B[8];   // vf at row y-1
    float v0C[8], v1C[8];   // vf at row y-2
    float oB[8];   // o at row y-1
    float p1B[8];  // p1' at row y-2
    float uB[8];   // u' at row y-2
    float qB2[8];  // q' at row y-2
#pragma unroll
    for (int i = 0; i < 8; ++i) {
        p1A[i]=0.f; uA[i]=0.f; qAr[i]=0.f; v0B[i]=0.f; v1B[i]=0.f;
        v0C[i]=0.f; v1C[i]=0.f; oB[i]=0.f; p1B[i]=0.f; uB[i]=0.f; qB2[i]=0.f;
    }

    for (int y = ylo; y <= yend; ++y) {
        const bool act = (y <= IMG_H - 1);
        float qi[8], oc[8], v0c[8], v1c[8];
        if (act) {
            const float* qr  = qin + ibase + (size_t)y * IMG_W;
            const float* orr = o   + ibase + (size_t)y * IMG_W;
            const float* vr  = vf  + (size_t)y * IMG_W * 2;
            float4 t4 = *(const float4*)(qr + x0);
            qi[2]=t4.x; qi[3]=t4.y; qi[4]=t4.z; qi[5]=t4.w;
            float4 o4 = *(const float4*)(orr + x0);
            oc[2]=o4.x; oc[3]=o4.y; oc[4]=o4.z; oc[5]=o4.w;
            float4 va = *(const float4*)(vr + 2*x0);
            float4 vb = *(const float4*)(vr + 2*x0 + 4);
            v0c[2]=va.x; v1c[2]=va.y; v0c[3]=va.z; v1c[3]=va.w;
            v0c[4]=vb.x; v1c[4]=vb.y; v0c[5]=vb.z; v1c[5]=vb.w;
            oc[0] = 0.f;
            if (!lft) {
                float2 q2 = *(const float2*)(qr + x0 - 2);
                qi[0]=q2.x; qi[1]=q2.y;
                oc[1] = orr[x0 - 1];
                float4 vm = *(const float4*)(vr + 2*x0 - 4);
                v0c[0]=vm.x; v1c[0]=vm.y; v0c[1]=vm.z; v1c[1]=vm.w;
            } else {
                qi[0]=qi[1]=0.f; oc[1]=0.f;
                v0c[0]=v1c[0]=v0c[1]=v1c[1]=0.f;
            }
            if (!rgt) {
                float2 q2 = *(const float2*)(qr + x0 + 4);
                qi[6]=q2.x; qi[7]=q2.y;
                float2 o2 = *(const float2*)(orr + x0 + 4);
                oc[6]=o2.x; oc[7]=o2.y;
                float4 vp = *(const float4*)(vr + 2*x0 + 8);
                v0c[6]=vp.x; v1c[6]=vp.y; v0c[7]=vp.z; v1c[7]=vp.w;
            } else {
                qi[6]=qi[7]=0.f; oc[6]=oc[7]=0.f;
                v0c[6]=v1c[6]=v0c[7]=v1c[7]=0.f;
            }
        } else {
#pragma unroll
            for (int i = 0; i < 8; ++i) { qi[i]=0.f; oc[i]=0.f; v0c[i]=0.f; v1c[i]=0.f; }
        }

        // ---- A: p0/p1 of q_i[y] ----
        float p0i[8], p1i[8];
#pragma unroll
        for (int i = 0; i < 8; ++i) { p0i[i] = v0c[i]*qi[i]; p1i[i] = v1c[i]*qi[i]; }
        if (lft) p0i[1] = 0.f;                 // p0 at px -1 = 0 (pad)

        // ---- B: u_i[y], i 1..7 ----
        float ui[8];
        ui[0] = 0.f;
#pragma unroll
        for (int i = 1; i < 8; ++i) {
            float Tq = p1i[i] - p1A[i] + p0i[i] - p0i[i-1];
            ui[i] = act ? sig2(oc[i] - Tq) : 0.f;   // y >= H -> u = 0 (pad)
        }
        if (rgt) { ui[6] = 0.f; ui[7] = 0.f; }      // px >= W -> u = 0 (pad)

        // ---- C: q' at z=y-1, i 1..6 ----
        const int z = y - 1;
        const bool cz = (z >= qp_lo) && (z <= r0 + RB) && (z <= IMG_H - 1);
        float qp[8], p0p[8], p1p[8];
#pragma unroll
        for (int i = 1; i < 7; ++i) {
            float qv = 0.f;
            if (cz) {
                float gy = ui[i] - uA[i];            // u[z+1]-u[z]
                float gx = uA[i+1] - uA[i];          // u[z][x+1]-u[z][x]
                qv = fmaxf(qAr[i] - 0.5f*(gy*v1B[i] + gx*v0B[i]), 0.f);
            }
            qp[i]  = qv;
            p0p[i] = v0B[i]*qv;
            p1p[i] = v1B[i]*qv;
        }
        if (lft) p0p[1] = 0.f;                 // p0' at px -1 = 0 (pad)

        // ---- D: u' at z, i 2..6 ----
        const bool dz = (z >= r0) && (z <= r0 + RB);
        float up[8];
#pragma unroll
        for (int i = 2; i < 7; ++i) {
            if (dz && z <= IMG_H - 1) {
                float Tqp = p1p[i] - p1B[i] + p0p[i] - p0p[i-1];
                up[i] = sig2(oB[i] - Tqp);
            } else {
                up[i] = 0.f;                   // z == H -> u' = 0 (pad)
            }
        }
        if (rgt) up[6] = 0.f;                  // px >= W -> u' = 0 (pad)

        // ---- E: q'' at w=z-1, i 2..5 -> global ----
        const int w = y - 2;
        if (w >= r0 && w <= r0 + RB - 1) {
            float qq[4];
#pragma unroll
            for (int i = 2; i < 6; ++i) {
                float gy = up[i] - uB[i];            // u'[w+1]-u'[w]
                float gx = uB[i+1] - uB[i];          // u'[w][x+1]-u'[w][x]
                qq[i-2] = fmaxf(qB2[i] - 0.5f*(gy*v1C[i] + gx*v0C[i]), 0.f);
            }
            *(float4*)(qout + ibase + (size_t)w * IMG_W + x0) =
                make_float4(qq[0], qq[1], qq[2], qq[3]);
        }

        // ---- rotate recurrences ----
#pragma unroll
        for (int i = 0; i < 8; ++i) p1A[i] = p1i[i];
#pragma unroll
        for (int i = 2; i < 6; ++i) { v0C[i] = v0B[i]; v1C[i] = v1B[i]; }
#pragma unroll
        for (int i = 0; i < 8; ++i) { v0B[i] = v0c[i]; v1B[i] = v1c[i]; }
#pragma unroll
        for (int i = 0; i < 8; ++i) { qAr[i] = qi[i]; uA[i] = ui[i]; }
#pragma unroll
        for (int i = 2; i < 7; ++i) { oB[i] = oc[i]; p1B[i] = p1p[i]; uB[i] = up[i]; }
#pragma unroll
        for (int i = 2; i < 6; ++i) qB2[i] = qp[i];
    }
}

// ---------------------------------------------------------------------------
// Barrier-free init depth-2: u0 = sig2(o) (q0 = 0), writes q2. Same pipeline
// minus stage A / q loads.
// ---------------------------------------------------------------------------
__global__ __launch_bounds__(TPB, 2) void k_init2(const float* __restrict__ o,
                                                  const float* __restrict__ vf,
                                                  float* __restrict__ qout) {
    const int img  = blockIdx.x / BANDS;
    const int r0   = (blockIdx.x % BANDS) * RB;
    const int x0   = threadIdx.x * 4;
    const bool topb = (r0 == 0);
    const bool lft  = (x0 == 0);
    const bool rgt  = (x0 == IMG_W - 4);
    const size_t ibase = (size_t)img * IMG_H * IMG_W;

    const int ylo   = topb ? 0 : r0 - 1;
    const int yend  = r0 + RB + 1;
    const int qp_lo = topb ? 0 : r0 - 1;

    float uA[8], v0B[8], v1B[8], v0C[8], v1C[8];
    float oB[8], p1B[8], uB[8], qB2[8];
#pragma unroll
    for (int i = 0; i < 8; ++i) {
        uA[i]=0.f; v0B[i]=0.f; v1B[i]=0.f; v0C[i]=0.f; v1C[i]=0.f;
        oB[i]=0.f; p1B[i]=0.f; uB[i]=0.f; qB2[i]=0.f;
    }

    for (int y = ylo; y <= yend; ++y) {
        const bool act = (y <= IMG_H - 1);
        float oc[8], v0c[8], v1c[8];
        if (act) {
            const float* orr = o  + ibase + (size_t)y * IMG_W;
            const float* vr  = vf + (size_t)y * IMG_W * 2;
            float4 o4 = *(const float4*)(orr + x0);
            oc[2]=o4.x; oc[3]=o4.y; oc[4]=o4.z; oc[5]=o4.w;
            float4 va = *(const float4*)(vr + 2*x0);
            float4 vb = *(const float4*)(vr + 2*x0 + 4);
            v0c[2]=va.x; v1c[2]=va.y; v0c[3]=va.z; v1c[3]=va.w;
            v0c[4]=vb.x; v1c[4]=vb.y; v0c[5]=vb.z; v1c[5]=vb.w;
            oc[0] = 0.f;
            if (!lft) {
                oc[1] = orr[x0 - 1];
                float4 vm = *(const float4*)(vr + 2*x0 - 4);
                v0c[0]=vm.x; v1c[0]=vm.y; v0c[1]=vm.z; v1c[1]=vm.w;
            } else {
                oc[1]=0.f; v0c[0]=v1c[0]=v0c[1]=v1c[1]=0.f;
            }
            if (!rgt) {
                float2 o2 = *(const float2*)(orr + x0 + 4);
                oc[6]=o2.x; oc[7]=o2.y;
                float4 vp = *(const float4*)(vr + 2*x0 + 8);
                v0c[6]=vp.x; v1c[6]=vp.y; v0c[7]=vp.z; v1c[7]=vp.w;
            } else {
                oc[6]=oc[7]=0.f; v0c[6]=v1c[6]=v0c[7]=v1c[7]=0.f;
            }
        } else {
#pragma unroll
            for (int i = 0; i < 8; ++i) { oc[i]=0.f; v0c[i]=0.f; v1c[i]=0.f; }
        }

        // ---- B: u0[y] = sig2(o) ----
        float ui[8];
        ui[0] = 0.f;
#pragma unroll
        for (int i = 1; i < 8; ++i) ui[i] = act ? sig2(oc[i]) : 0.f;
        if (rgt) { ui[6] = 0.f; ui[7] = 0.f; }

        // ---- C: q1 at z=y-1 (q0 = 0) ----
        const int z = y - 1;
        const bool cz = (z >= qp_lo) && (z <= r0 + RB) && (z <= IMG_H - 1);
        float qp[8], p0p[8], p1p[8];
#pragma unroll
        for (int i = 1; i < 7; ++i) {
            float qv = 0.f;
            if (cz) {
                float gy = ui[i] - uA[i];
                float gx = uA[i+1] - uA[i];
                qv = fmaxf(-0.5f*(gy*v1B[i] + gx*v0B[i]), 0.f);
            }
            qp[i]  = qv;
            p0p[i] = v0B[i]*qv;
            p1p[i] = v1B[i]*qv;
        }
        if (lft) p0p[1] = 0.f;

        // ---- D: u1 at z ----
        const bool dz = (z >= r0) && (z <= r0 + RB);
        float up[8];
#pragma unroll
        for (int i = 2; i < 7; ++i) {
            if (dz && z <= IMG_H - 1) {
                float Tqp = p1p[i] - p1B[i] + p0p[i] - p0p[i-1];
                up[i] = sig2(oB[i] - Tqp);
            } else {
                up[i] = 0.f;
            }
        }
        if (rgt) up[6] = 0.f;

        // ---- E: q2 at w=z-1 -> global ----
        const int w = y - 2;
        if (w >= r0 && w <= r0 + RB - 1) {
            float qq[4];
#pragma unroll
            for (int i = 2; i < 6; ++i) {
                float gy = up[i] - uB[i];
                float gx = uB[i+1] - uB[i];
                qq[i-2] = fmaxf(qB2[i] - 0.5f*(gy*v1C[i] + gx*v0C[i]), 0.f);
            }
            *(float4*)(qout + ibase + (size_t)w * IMG_W + x0) =
                make_float4(qq[0], qq[1], qq[2], qq[3]);
        }

        // ---- rotate ----
#pragma unroll
        for (int i = 2; i < 6; ++i) { v0C[i] = v0B[i]; v1C[i] = v1B[i]; }
#pragma unroll
        for (int i = 0; i < 8; ++i) { v0B[i] = v0c[i]; v1B[i] = v1c[i]; }
#pragma unroll
        for (int i = 0; i < 8; ++i) uA[i] = ui[i];
#pragma unroll
        for (int i = 2; i < 7; ++i) { oB[i] = oc[i]; p1B[i] = p1p[i]; uB[i] = up[i]; }
#pragma unroll
        for (int i = 2; i < 6; ++i) qB2[i] = qp[i];
    }
}

// ---------------------------------------------------------------------------
// Final: out = 2*(o - Tq(q10)). One row per block. (Round-2/5 verified.)
// ---------------------------------------------------------------------------
__global__ __launch_bounds__(TPB) void k_final(const float* __restrict__ q,
                                               const float* __restrict__ vf,
                                               const float* __restrict__ o,
                                               float* __restrict__ out) {
    __shared__ __align__(16) float sp0[IMG_W + 4];
    const int row = blockIdx.x & (IMG_H - 1);
    const int x0  = threadIdx.x * 4;
    const size_t base = (size_t)blockIdx.x * IMG_W;

    float4 q4 = *(const float4*)(q + base + x0);
    const size_t vbase = ((size_t)row * IMG_W + x0) * 2;
    float4 vfa = *(const float4*)(vf + vbase);
    float4 vfb = *(const float4*)(vf + vbase + 4);

    const float v0[4] = {vfa.x, vfa.z, vfb.x, vfb.z};
    const float v1[4] = {vfa.y, vfa.w, vfb.y, vfb.w};
    const float qc[4] = {q4.x, q4.y, q4.z, q4.w};

    float p0[4], p1[4];
#pragma unroll
    for (int j = 0; j < 4; ++j) {
        p0[j] = v0[j] * qc[j];
        p1[j] = v1[j] * qc[j];
        sp0[x0 + j + 1] = p0[j];
    }
    if (threadIdx.x == 0) sp0[0] = 0.0f;

    float p1m[4];
    if (row > 0) {
        float4 qm  = *(const float4*)(q + base - IMG_W + x0);
        float4 vma = *(const float4*)(vf + vbase - 2 * IMG_W);
        float4 vmb = *(const float4*)(vf + vbase - 2 * IMG_W + 4);
        p1m[0] = qm.x * vma.y; p1m[1] = qm.y * vma.w;
        p1m[2] = qm.z * vmb.y; p1m[3] = qm.w * vmb.w;
    } else {
        p1m[0] = p1m[1] = p1m[2] = p1m[3] = 0.0f;
    }

    float4 o4 = *(const float4*)(o + base + x0);
    const float oc[4] = {o4.x, o4.y, o4.z, o4.w};

    __syncthreads();

    float r[4];
#pragma unroll
    for (int j = 0; j < 4; ++j) {
        float Tq = p1[j] - p1m[j] + p0[j] - sp0[x0 + j];
        r[j] = 2.0f * (oc[j] - Tq);
    }
    *(float4*)(out + base + x0) = make_float4(r[0], r[1], r[2], r[3]);
}

extern "C" void kernel_launch(void* const* d_in, const int* in_sizes, int n_in,
                              void* d_out, int out_size, void* d_ws, size_t ws_size,
                              hipStream_t stream) {
    const float* o  = (const float*)d_in[0];
    const float* vf = (const float*)d_in[1];

    float* bufA = (float*)d_ws;    // q2, q6, q10
    float* bufB = (float*)d_out;   // q4, q8 (overwritten by final output)

    k_init2 <<<NBLK, TPB, 0, stream>>>(o, vf, bufA);         // q2  -> A
    k_fused2<<<NBLK, TPB, 0, stream>>>(bufA, vf, o, bufB);   // q4  -> B
    k_fused2<<<NBLK, TPB, 0, stream>>>(bufB, vf, o, bufA);   // q6  -> A
    k_fused2<<<NBLK, TPB, 0, stream>>>(bufA, vf, o, bufB);   // q8  -> B
    k_fused2<<<NBLK, TPB, 0, stream>>>(bufB, vf, o, bufA);   // q10 -> A
    k_final <<<IMG_B * IMG_H, TPB, 0, stream>>>(bufA, vf, o, (float*)d_out);
}

// Round 7
// 313.927 us; speedup vs baseline: 1.0392x; 1.0392x over previous
//
#include <hip/hip_runtime.h>
#include <math.h>

#define IMG_H 1024
#define IMG_W 1024
#define IMG_B 8
#define TPB 256                    // 256 thr * 4 px = one full row
#define RB 8                       // output rows per band
#define BANDS (IMG_H / RB)         // 128
#define NBLK (IMG_B * BANDS)       // 1024 blocks = 4/CU -> 16 waves/CU

__device__ __forceinline__ float sig2(float x) {   // sigmoid(2x) == sigmoid(x/EPS)
    return 1.0f / (1.0f + __expf(-2.0f * x));
}

// ---------------------------------------------------------------------------
// Barrier-free depth-2 fused kernel. Thread owns px [x0, x0+3]; computes the
// full 2-iteration pipeline on a shrinking halo window [x0-2 .. x0+5] held in
// registers. Fixed 12-trip band sweep (y = r0-2 .. r0+RB+1), fully guarded,
// unrolled so the compiler renames carried registers instead of copying.
// No LDS, no __syncthreads.
// ---------------------------------------------------------------------------
__global__ __launch_bounds__(TPB, 4) void k_fused2(const float* __restrict__ qin,
                                                   const float* __restrict__ vf,
                                                   const float* __restrict__ o,
                                                   float* __restrict__ qout) {
    const int img  = blockIdx.x / BANDS;
    const int r0   = (blockIdx.x % BANDS) * RB;
    const int x0   = threadIdx.x * 4;
    const bool lft  = (x0 == 0);
    const bool rgt  = (x0 == IMG_W - 4);
    const size_t ibase = (size_t)img * IMG_H * IMG_W;

    const int qp_lo = (r0 == 0) ? 0 : r0 - 1;   // first row where q' is real

    // carried row-recurrence state
    float p1A[8];  // p1 of q_i at row y-1
    float uA[8];   // u_i at row y-1
    float qAr[8];  // q_i at row y-1
    float v0B[8], v1B[8];   // vf at row y-1
    float v0C[8], v1C[8];   // vf at row y-2
    float oB[8];   // o at row y-1
    float p1B[8];  // p1' at row y-2
    float uB[8];   // u' at row y-2
    float qB2[8];  // q' at row y-2
#pragma unroll
    for (int i = 0; i < 8; ++i) {
        p1A[i]=0.f; uA[i]=0.f; qAr[i]=0.f; v0B[i]=0.f; v1B[i]=0.f;
        v0C[i]=0.f; v1C[i]=0.f; oB[i]=0.f; p1B[i]=0.f; uB[i]=0.f; qB2[i]=0.f;
    }

#pragma unroll 4
    for (int t = 0; t < RB + 4; ++t) {
        const int y = r0 - 2 + t;
        const bool act = (y >= 0) && (y <= IMG_H - 1);
        float qi[8], oc[8], v0c[8], v1c[8];
        if (act) {
            const float* qr  = qin + ibase + (size_t)y * IMG_W;
            const float* orr = o   + ibase + (size_t)y * IMG_W;
            const float* vr  = vf  + (size_t)y * IMG_W * 2;
            float4 t4 = *(const float4*)(qr + x0);
            qi[2]=t4.x; qi[3]=t4.y; qi[4]=t4.z; qi[5]=t4.w;
            float4 o4 = *(const float4*)(orr + x0);
            oc[2]=o4.x; oc[3]=o4.y; oc[4]=o4.z; oc[5]=o4.w;
            float4 va = *(const float4*)(vr + 2*x0);
            float4 vb = *(const float4*)(vr + 2*x0 + 4);
            v0c[2]=va.x; v1c[2]=va.y; v0c[3]=va.z; v1c[3]=va.w;
            v0c[4]=vb.x; v1c[4]=vb.y; v0c[5]=vb.z; v1c[5]=vb.w;
            oc[0] = 0.f;
            if (!lft) {
                float2 q2 = *(const float2*)(qr + x0 - 2);
                qi[0]=q2.x; qi[1]=q2.y;
                oc[1] = orr[x0 - 1];
                float4 vm = *(const float4*)(vr + 2*x0 - 4);
                v0c[0]=vm.x; v1c[0]=vm.y; v0c[1]=vm.z; v1c[1]=vm.w;
            } else {
                qi[0]=qi[1]=0.f; oc[1]=0.f;
                v0c[0]=v1c[0]=v0c[1]=v1c[1]=0.f;
            }
            if (!rgt) {
                float2 q2 = *(const float2*)(qr + x0 + 4);
                qi[6]=q2.x; qi[7]=q2.y;
                float2 o2 = *(const float2*)(orr + x0 + 4);
                oc[6]=o2.x; oc[7]=o2.y;
                float4 vp = *(const float4*)(vr + 2*x0 + 8);
                v0c[6]=vp.x; v1c[6]=vp.y; v0c[7]=vp.z; v1c[7]=vp.w;
            } else {
                qi[6]=qi[7]=0.f; oc[6]=oc[7]=0.f;
                v0c[6]=v1c[6]=v0c[7]=v1c[7]=0.f;
            }
        } else {
#pragma unroll
            for (int i = 0; i < 8; ++i) { qi[i]=0.f; oc[i]=0.f; v0c[i]=0.f; v1c[i]=0.f; }
        }

        // ---- A: p0/p1 of q_i[y] ----
        float p0i[8], p1i[8];
#pragma unroll
        for (int i = 0; i < 8; ++i) { p0i[i] = v0c[i]*qi[i]; p1i[i] = v1c[i]*qi[i]; }
        if (lft) p0i[1] = 0.f;                 // p0 at px -1 = 0 (pad)

        // ---- B: u_i[y], i 1..7 ----
        float ui[8];
        ui[0] = 0.f;
#pragma unroll
        for (int i = 1; i < 8; ++i) {
            float Tq = p1i[i] - p1A[i] + p0i[i] - p0i[i-1];
            ui[i] = act ? sig2(oc[i] - Tq) : 0.f;   // y out of range -> u = 0 (pad)
        }
        if (rgt) { ui[6] = 0.f; ui[7] = 0.f; }      // px >= W -> u = 0 (pad)

        // ---- C: q' at z=y-1, i 1..6 ----
        const int z = y - 1;
        const bool cz = (z >= qp_lo) && (z <= r0 + RB) && (z <= IMG_H - 1);
        float qp[8], p0p[8], p1p[8];
#pragma unroll
        for (int i = 1; i < 7; ++i) {
            float qv = 0.f;
            if (cz) {
                float gy = ui[i] - uA[i];            // u[z+1]-u[z]
                float gx = uA[i+1] - uA[i];          // u[z][x+1]-u[z][x]
                qv = fmaxf(qAr[i] - 0.5f*(gy*v1B[i] + gx*v0B[i]), 0.f);
            }
            qp[i]  = qv;
            p0p[i] = v0B[i]*qv;
            p1p[i] = v1B[i]*qv;
        }
        if (lft) p0p[1] = 0.f;                 // p0' at px -1 = 0 (pad)

        // ---- D: u' at z, i 2..6 ----
        const bool dz = (z >= r0) && (z <= r0 + RB);
        float up[8];
#pragma unroll
        for (int i = 2; i < 7; ++i) {
            if (dz && z <= IMG_H - 1) {
                float Tqp = p1p[i] - p1B[i] + p0p[i] - p0p[i-1];
                up[i] = sig2(oB[i] - Tqp);
            } else {
                up[i] = 0.f;                   // z == H -> u' = 0 (pad)
            }
        }
        if (rgt) up[6] = 0.f;                  // px >= W -> u' = 0 (pad)

        // ---- E: q'' at w=z-1, i 2..5 -> global ----
        const int w = y - 2;
        if (w >= r0 && w <= r0 + RB - 1) {
            float qq[4];
#pragma unroll
            for (int i = 2; i < 6; ++i) {
                float gy = up[i] - uB[i];            // u'[w+1]-u'[w]
                float gx = uB[i+1] - uB[i];          // u'[w][x+1]-u'[w][x]
                qq[i-2] = fmaxf(qB2[i] - 0.5f*(gy*v1C[i] + gx*v0C[i]), 0.f);
            }
            *(float4*)(qout + ibase + (size_t)w * IMG_W + x0) =
                make_float4(qq[0], qq[1], qq[2], qq[3]);
        }

        // ---- rotate recurrences (renamed away by unroll) ----
#pragma unroll
        for (int i = 0; i < 8; ++i) p1A[i] = p1i[i];
#pragma unroll
        for (int i = 2; i < 6; ++i) { v0C[i] = v0B[i]; v1C[i] = v1B[i]; }
#pragma unroll
        for (int i = 0; i < 8; ++i) { v0B[i] = v0c[i]; v1B[i] = v1c[i]; }
#pragma unroll
        for (int i = 0; i < 8; ++i) { qAr[i] = qi[i]; uA[i] = ui[i]; }
#pragma unroll
        for (int i = 2; i < 7; ++i) { oB[i] = oc[i]; p1B[i] = p1p[i]; uB[i] = up[i]; }
#pragma unroll
        for (int i = 2; i < 6; ++i) qB2[i] = qp[i];
    }
}

// ---------------------------------------------------------------------------
// Barrier-free init depth-2: u0 = sig2(o) (q0 = 0), writes q2. Fixed 11-trip
// sweep (y = r0-1 .. r0+RB+1).
// ---------------------------------------------------------------------------
__global__ __launch_bounds__(TPB, 4) void k_init2(const float* __restrict__ o,
                                                  const float* __restrict__ vf,
                                                  float* __restrict__ qout) {
    const int img  = blockIdx.x / BANDS;
    const int r0   = (blockIdx.x % BANDS) * RB;
    const int x0   = threadIdx.x * 4;
    const bool lft  = (x0 == 0);
    const bool rgt  = (x0 == IMG_W - 4);
    const size_t ibase = (size_t)img * IMG_H * IMG_W;

    const int qp_lo = (r0 == 0) ? 0 : r0 - 1;

    float uA[8], v0B[8], v1B[8], v0C[8], v1C[8];
    float oB[8], p1B[8], uB[8], qB2[8];
#pragma unroll
    for (int i = 0; i < 8; ++i) {
        uA[i]=0.f; v0B[i]=0.f; v1B[i]=0.f; v0C[i]=0.f; v1C[i]=0.f;
        oB[i]=0.f; p1B[i]=0.f; uB[i]=0.f; qB2[i]=0.f;
    }

#pragma unroll 4
    for (int t = 0; t < RB + 3; ++t) {
        const int y = r0 - 1 + t;
        const bool act = (y >= 0) && (y <= IMG_H - 1);
        float oc[8], v0c[8], v1c[8];
        if (act) {
            const float* orr = o  + ibase + (size_t)y * IMG_W;
            const float* vr  = vf + (size_t)y * IMG_W * 2;
            float4 o4 = *(const float4*)(orr + x0);
            oc[2]=o4.x; oc[3]=o4.y; oc[4]=o4.z; oc[5]=o4.w;
            float4 va = *(const float4*)(vr + 2*x0);
            float4 vb = *(const float4*)(vr + 2*x0 + 4);
            v0c[2]=va.x; v1c[2]=va.y; v0c[3]=va.z; v1c[3]=va.w;
            v0c[4]=vb.x; v1c[4]=vb.y; v0c[5]=vb.z; v1c[5]=vb.w;
            oc[0] = 0.f;
            if (!lft) {
                oc[1] = orr[x0 - 1];
                float4 vm = *(const float4*)(vr + 2*x0 - 4);
                v0c[0]=vm.x; v1c[0]=vm.y; v0c[1]=vm.z; v1c[1]=vm.w;
            } else {
                oc[1]=0.f; v0c[0]=v1c[0]=v0c[1]=v1c[1]=0.f;
            }
            if (!rgt) {
                float2 o2 = *(const float2*)(orr + x0 + 4);
                oc[6]=o2.x; oc[7]=o2.y;
                float4 vp = *(const float4*)(vr + 2*x0 + 8);
                v0c[6]=vp.x; v1c[6]=vp.y; v0c[7]=vp.z; v1c[7]=vp.w;
            } else {
                oc[6]=oc[7]=0.f; v0c[6]=v1c[6]=v0c[7]=v1c[7]=0.f;
            }
        } else {
#pragma unroll
            for (int i = 0; i < 8; ++i) { oc[i]=0.f; v0c[i]=0.f; v1c[i]=0.f; }
        }

        // ---- B: u0[y] = sig2(o) ----
        float ui[8];
        ui[0] = 0.f;
#pragma unroll
        for (int i = 1; i < 8; ++i) ui[i] = act ? sig2(oc[i]) : 0.f;
        if (rgt) { ui[6] = 0.f; ui[7] = 0.f; }

        // ---- C: q1 at z=y-1 (q0 = 0) ----
        const int z = y - 1;
        const bool cz = (z >= qp_lo) && (z <= r0 + RB) && (z <= IMG_H - 1);
        float qp[8], p0p[8], p1p[8];
#pragma unroll
        for (int i = 1; i < 7; ++i) {
            float qv = 0.f;
            if (cz) {
                float gy = ui[i] - uA[i];
                float gx = uA[i+1] - uA[i];
                qv = fmaxf(-0.5f*(gy*v1B[i] + gx*v0B[i]), 0.f);
            }
            qp[i]  = qv;
            p0p[i] = v0B[i]*qv;
            p1p[i] = v1B[i]*qv;
        }
        if (lft) p0p[1] = 0.f;

        // ---- D: u1 at z ----
        const bool dz = (z >= r0) && (z <= r0 + RB);
        float up[8];
#pragma unroll
        for (int i = 2; i < 7; ++i) {
            if (dz && z <= IMG_H - 1) {
                float Tqp = p1p[i] - p1B[i] + p0p[i] - p0p[i-1];
                up[i] = sig2(oB[i] - Tqp);
            } else {
                up[i] = 0.f;
            }
        }
        if (rgt) up[6] = 0.f;

        // ---- E: q2 at w=z-1 -> global ----
        const int w = y - 2;
        if (w >= r0 && w <= r0 + RB - 1) {
            float qq[4];
#pragma unroll
            for (int i = 2; i < 6; ++i) {
                float gy = up[i] - uB[i];
                float gx = uB[i+1] - uB[i];
                qq[i-2] = fmaxf(qB2[i] - 0.5f*(gy*v1C[i] + gx*v0C[i]), 0.f);
            }
            *(float4*)(qout + ibase + (size_t)w * IMG_W + x0) =
                make_float4(qq[0], qq[1], qq[2], qq[3]);
        }

        // ---- rotate ----
#pragma unroll
        for (int i = 2; i < 6; ++i) { v0C[i] = v0B[i]; v1C[i] = v1B[i]; }
#pragma unroll
        for (int i = 0; i < 8; ++i) { v0B[i] = v0c[i]; v1B[i] = v1c[i]; }
#pragma unroll
        for (int i = 0; i < 8; ++i) uA[i] = ui[i];
#pragma unroll
        for (int i = 2; i < 7; ++i) { oB[i] = oc[i]; p1B[i] = p1p[i]; uB[i] = up[i]; }
#pragma unroll
        for (int i = 2; i < 6; ++i) qB2[i] = qp[i];
    }
}

// ---------------------------------------------------------------------------
// Final: out = 2*(o - Tq(q10)). One row per block. (Round-2/5 verified.)
// ---------------------------------------------------------------------------
__global__ __launch_bounds__(TPB) void k_final(const float* __restrict__ q,
                                               const float* __restrict__ vf,
                                               const float* __restrict__ o,
                                               float* __restrict__ out) {
    __shared__ __align__(16) float sp0[IMG_W + 4];
    const int row = blockIdx.x & (IMG_H - 1);
    const int x0  = threadIdx.x * 4;
    const size_t base = (size_t)blockIdx.x * IMG_W;

    float4 q4 = *(const float4*)(q + base + x0);
    const size_t vbase = ((size_t)row * IMG_W + x0) * 2;
    float4 vfa = *(const float4*)(vf + vbase);
    float4 vfb = *(const float4*)(vf + vbase + 4);

    const float v0[4] = {vfa.x, vfa.z, vfb.x, vfb.z};
    const float v1[4] = {vfa.y, vfa.w, vfb.y, vfb.w};
    const float qc[4] = {q4.x, q4.y, q4.z, q4.w};

    float p0[4], p1[4];
#pragma unroll
    for (int j = 0; j < 4; ++j) {
        p0[j] = v0[j] * qc[j];
        p1[j] = v1[j] * qc[j];
        sp0[x0 + j + 1] = p0[j];
    }
    if (threadIdx.x == 0) sp0[0] = 0.0f;

    float p1m[4];
    if (row > 0) {
        float4 qm  = *(const float4*)(q + base - IMG_W + x0);
        float4 vma = *(const float4*)(vf + vbase - 2 * IMG_W);
        float4 vmb = *(const float4*)(vf + vbase - 2 * IMG_W + 4);
        p1m[0] = qm.x * vma.y; p1m[1] = qm.y * vma.w;
        p1m[2] = qm.z * vmb.y; p1m[3] = qm.w * vmb.w;
    } else {
        p1m[0] = p1m[1] = p1m[2] = p1m[3] = 0.0f;
    }

    float4 o4 = *(const float4*)(o + base + x0);
    const float oc[4] = {o4.x, o4.y, o4.z, o4.w};

    __syncthreads();

    float r[4];
#pragma unroll
    for (int j = 0; j < 4; ++j) {
        float Tq = p1[j] - p1m[j] + p0[j] - sp0[x0 + j];
        r[j] = 2.0f * (oc[j] - Tq);
    }
    *(float4*)(out + base + x0) = make_float4(r[0], r[1], r[2], r[3]);
}

extern "C" void kernel_launch(void* const* d_in, const int* in_sizes, int n_in,
                              void* d_out, int out_size, void* d_ws, size_t ws_size,
                              hipStream_t stream) {
    const float* o  = (const float*)d_in[0];
    const float* vf = (const float*)d_in[1];

    float* bufA = (float*)d_ws;    // q2, q6, q10
    float* bufB = (float*)d_out;   // q4, q8 (overwritten by final output)

    k_init2 <<<NBLK, TPB, 0, stream>>>(o, vf, bufA);         // q2  -> A
    k_fused2<<<NBLK, TPB, 0, stream>>>(bufA, vf, o, bufB);   // q4  -> B
    k_fused2<<<NBLK, TPB, 0, stream>>>(bufB, vf, o, bufA);   // q6  -> A
    k_fused2<<<NBLK, TPB, 0, stream>>>(bufA, vf, o, bufB);   // q8  -> B
    k_fused2<<<NBLK, TPB, 0, stream>>>(bufB, vf, o, bufA);   // q10 -> A
    k_final <<<IMG_B * IMG_H, TPB, 0, stream>>>(bufA, vf, o, (float*)d_out);
}

// Round 9
// 269.941 us; speedup vs baseline: 1.2085x; 1.1629x over previous
//
#include <hip/hip_runtime.h>
#include <math.h>

#define IMG_H 1024
#define IMG_W 1024
#define IMG_B 8
#define TPB 256                    // 256 thr * 4 px = one full row
#define RB 8                       // output rows per band
#define BANDS (IMG_H / RB)         // 128
#define NBLK (IMG_B * BANDS)       // 1024 blocks = 4/CU

__device__ __forceinline__ float sig2(float x) {   // sigmoid(2x) == sigmoid(x/EPS)
    return 1.0f / (1.0f + __expf(-2.0f * x));
}

// ---------------------------------------------------------------------------
// Depth-2 fused, skinny threads: thread owns exactly px [x0,x0+3]; the 1-px
// stage shrinks are refilled by wave shuffles. Wave-edge lanes (0/63) carry a
// 2-px halo pair and patch the shuffle. No LDS, no barriers.
// Pair mapping: lane0 -> (x0-2, x0-1) [provides p0/p0' at x0-1],
//               lane63 -> (x0+4, x0+5) [provides u/u' at x0+4].
// Pad semantics: q (hence p0/p1) is ZERO for rows outside [0,H) -> qi/qa/qb
// zeroed when !act (this was the round-8 bug: clamped-row p1 leaked into p1A).
// ---------------------------------------------------------------------------
__global__ __launch_bounds__(TPB, 4) void k_fused2(const float* __restrict__ qin,
                                                   const float* __restrict__ vf,
                                                   const float* __restrict__ o,
                                                   float* __restrict__ qout) {
    const int img  = blockIdx.x / BANDS;
    const int r0   = (blockIdx.x % BANDS) * RB;
    const int tid  = (int)threadIdx.x;
    const int lane = tid & 63;
    const int x0   = tid * 4;
    const bool is_l0  = (lane == 0);
    const bool is_l63 = (lane == 63);
    const bool edge   = is_l0 || is_l63;
    const bool pair_valid = is_l63 ? (x0 != IMG_W - 4) : (x0 != 0);
    int pA = is_l63 ? (x0 + 4) : (x0 - 2);
    if (pA < 0) pA = 0;
    if (pA > IMG_W - 2) pA = IMG_W - 2;
    const size_t ibase = (size_t)img * IMG_H * IMG_W;
    const int qp_lo = (r0 == 0) ? 0 : r0 - 1;

    // interior carried recurrences (rows y-1 / y-2)
    float p1A[4], uA[4], qAr[4], v0B[4], v1B[4], oB[4], p1B[4], uB[4], qB2[4], v0C[4], v1C[4];
#pragma unroll
    for (int j = 0; j < 4; ++j) {
        p1A[j]=0.f; uA[j]=0.f; qAr[j]=0.f; v0B[j]=0.f; v1B[j]=0.f; oB[j]=0.f;
        p1B[j]=0.f; uB[j]=0.f; qB2[j]=0.f; v0C[j]=0.f; v1C[j]=0.f;
    }
    float uA4 = 0.f, uB4 = 0.f;
    // pair carried + pair loads (only edge lanes update loads)
    float p1Aa=0.f,p1Ab=0.f,uAa=0.f,uAb=0.f,qAra=0.f,qArb=0.f;
    float v0Ba=0.f,v1Ba=0.f,v0Bb=0.f,v1Bb=0.f,oBa=0.f,p1Ba=0.f;
    float qa=0.f,qb=0.f,oa=0.f,ob=0.f,v0a=0.f,v1a=0.f,v0b=0.f,v1b=0.f;

    for (int t = 0; t < RB + 4; ++t) {
        const int y = r0 - 2 + t;
        const bool act = (y >= 0) && (y < IMG_H);
        const int yc = (y < 0) ? 0 : ((y > IMG_H - 1) ? IMG_H - 1 : y);
        const float* qr  = qin + ibase + (size_t)yc * IMG_W;
        const float* orr = o   + ibase + (size_t)yc * IMG_W;
        const float* vr  = vf  + (size_t)yc * IMG_W * 2;

        // own loads (clamped row); q zeroed for pad rows (p = vf*q pads to 0)
        float4 q4 = *(const float4*)(qr + x0);
        float4 o4 = *(const float4*)(orr + x0);
        float4 va = *(const float4*)(vr + 2 * x0);
        float4 vb = *(const float4*)(vr + 2 * x0 + 4);
        float qi[4]  = {q4.x, q4.y, q4.z, q4.w};
        float oc[4]  = {o4.x, o4.y, o4.z, o4.w};
        float v0c[4] = {va.x, va.z, vb.x, vb.z};
        float v1c[4] = {va.y, va.w, vb.y, vb.w};
        if (!act) { qi[0]=0.f; qi[1]=0.f; qi[2]=0.f; qi[3]=0.f; }

        // pair loads (edge lanes only)
        if (edge) {
            float2 qp2 = *(const float2*)(qr + pA);
            float2 op2 = *(const float2*)(orr + pA);
            float4 vp4 = *(const float4*)(vr + 2 * pA);
            if (pair_valid && act) {
                qa = qp2.x; qb = qp2.y; oa = op2.x; ob = op2.y;
                v0a = vp4.x; v1a = vp4.y; v0b = vp4.z; v1b = vp4.w;
            } else {
                qa=0.f; qb=0.f; oa=0.f; ob=0.f; v0a=0.f; v1a=0.f; v0b=0.f; v1b=0.f;
            }
        }

        // ---- A: p0/p1 ----
        float p0i[4], p1i[4];
#pragma unroll
        for (int j = 0; j < 4; ++j) { p0i[j] = v0c[j]*qi[j]; p1i[j] = v1c[j]*qi[j]; }
        float p0a = v0a*qa, p1a = v1a*qa, p0b = v0b*qb, p1b = v1b*qb;

        // X1: p0 at x0-1
        float sh1 = __shfl_up(p0i[3], 1);
        float p0left = is_l0 ? p0b : sh1;      // lft image edge: p0b==0 (zeroed pair)

        // ---- B: u at row y ----
        float ui[4];
        {
            float Tq0 = p1i[0] - p1A[0] + p0i[0] - p0left;
            ui[0] = act ? sig2(oc[0] - Tq0) : 0.f;
#pragma unroll
            for (int j = 1; j < 4; ++j) {
                float Tq = p1i[j] - p1A[j] + p0i[j] - p0i[j-1];
                ui[j] = act ? sig2(oc[j] - Tq) : 0.f;
            }
        }
        // pair B (ua only meaningful for lane63; ub for lane0)
        float pbA = is_l63 ? p0i[3] : 0.f;     // p0 just left of pair-a
        float ua = (act && pair_valid) ? sig2(oa - (p1a - p1Aa + p0a - pbA)) : 0.f;
        float ub = (act && pair_valid) ? sig2(ob - (p1b - p1Ab + p0b - p0a)) : 0.f;

        // X2: u at x0+4 (row y)
        float sh2 = __shfl_down(ui[0], 1);
        float u4 = is_l63 ? ua : sh2;          // rgt image edge: ua==0 (x pad)

        // ---- C: q' at row z = y-1 ----
        const int z = y - 1;
        const bool cz = (z >= qp_lo) && (z <= r0 + RB) && (z < IMG_H);
        float qp[4], p0p[4], p1p[4];
#pragma unroll
        for (int j = 0; j < 4; ++j) {
            float gy = ui[j] - uA[j];
            float gx = ((j < 3) ? uA[j+1] : uA4) - uA[j];
            float qv = cz ? fmaxf(qAr[j] - 0.5f*(gy*v1B[j] + gx*v0B[j]), 0.f) : 0.f;
            qp[j] = qv; p0p[j] = v0B[j]*qv; p1p[j] = v1B[j]*qv;
        }
        // pair C
        float gya = ua - uAa, gxa = uAb - uAa;
        float qpa = cz ? fmaxf(qAra - 0.5f*(gya*v1Ba + gxa*v0Ba), 0.f) : 0.f;
        float gyb = ub - uAb, gxb = uA[0] - uAb;   // right neighbor of pair-b is own px x0
        float qpb = cz ? fmaxf(qArb - 0.5f*(gyb*v1Bb + gxb*v0Bb), 0.f) : 0.f;
        float p0pa = v0Ba*qpa, p1pa = v1Ba*qpa, p0pb = v0Bb*qpb;

        // X3: p0' at x0-1
        float sh3 = __shfl_up(p0p[3], 1);
        float p0pleft = is_l0 ? p0pb : sh3;    // lft image edge: v0Bb==0 -> 0

        // ---- D: u' at row z ----
        const bool dz = (z >= r0) && (z <= r0 + RB) && (z < IMG_H);
        float up[4];
        {
            float Tqp0 = p1p[0] - p1B[0] + p0p[0] - p0pleft;
            up[0] = dz ? sig2(oB[0] - Tqp0) : 0.f;
#pragma unroll
            for (int j = 1; j < 4; ++j) {
                float Tqp = p1p[j] - p1B[j] + p0p[j] - p0p[j-1];
                up[j] = dz ? sig2(oB[j] - Tqp) : 0.f;
            }
        }
        // pair D (lane63 needs u' at x0+4; p0' just left of pair-a = own p0p[3])
        float upa = (dz && pair_valid) ? sig2(oBa - (p1pa - p1Ba + p0pa - p0p[3])) : 0.f;

        // X4: u' at x0+4 (row z)
        float sh4 = __shfl_down(up[0], 1);
        float up4 = is_l63 ? upa : sh4;        // rgt image edge: 0 (x pad)

        // ---- E: q'' at row w = y-2 -> global ----
        const int w = y - 2;
        if (w >= r0 && w <= r0 + RB - 1) {
            float qq[4];
#pragma unroll
            for (int j = 0; j < 4; ++j) {
                float gy = up[j] - uB[j];
                float gx = ((j < 3) ? uB[j+1] : uB4) - uB[j];
                qq[j] = fmaxf(qB2[j] - 0.5f*(gy*v1C[j] + gx*v0C[j]), 0.f);
            }
            *(float4*)(qout + ibase + (size_t)w * IMG_W + x0) =
                make_float4(qq[0], qq[1], qq[2], qq[3]);
        }

        // ---- rotate ----
#pragma unroll
        for (int j = 0; j < 4; ++j) {
            v0C[j] = v0B[j]; v1C[j] = v1B[j];          // row y-2 <- y-1 (before overwrite)
            p1A[j] = p1i[j]; uA[j] = ui[j]; qAr[j] = qi[j];
            v0B[j] = v0c[j]; v1B[j] = v1c[j]; oB[j] = oc[j];
            p1B[j] = p1p[j]; uB[j] = up[j]; qB2[j] = qp[j];
        }
        uA4 = u4; uB4 = up4;
        p1Aa = p1a; p1Ab = p1b; uAa = ua; uAb = ub; qAra = qa; qArb = qb;
        v0Ba = v0a; v1Ba = v1a; v0Bb = v0b; v1Bb = v1b; oBa = oa; p1Ba = p1pa;
    }
}

// ---------------------------------------------------------------------------
// Init depth-2 (q0=0, u0 = sig2(o)): same skinny scheme minus stage A / X1.
// (No q-path here, so no pad-row contamination: all p' terms are cz-guarded.)
// ---------------------------------------------------------------------------
__global__ __launch_bounds__(TPB, 4) void k_init2(const float* __restrict__ o,
                                                  const float* __restrict__ vf,
                                                  float* __restrict__ qout) {
    const int img  = blockIdx.x / BANDS;
    const int r0   = (blockIdx.x % BANDS) * RB;
    const int tid  = (int)threadIdx.x;
    const int lane = tid & 63;
    const int x0   = tid * 4;
    const bool is_l0  = (lane == 0);
    const bool is_l63 = (lane == 63);
    const bool edge   = is_l0 || is_l63;
    const bool pair_valid = is_l63 ? (x0 != IMG_W - 4) : (x0 != 0);
    int pA = is_l63 ? (x0 + 4) : (x0 - 2);
    if (pA < 0) pA = 0;
    if (pA > IMG_W - 2) pA = IMG_W - 2;
    const size_t ibase = (size_t)img * IMG_H * IMG_W;
    const int qp_lo = (r0 == 0) ? 0 : r0 - 1;

    float uA[4], v0B[4], v1B[4], oB[4], p1B[4], uB[4], qB2[4], v0C[4], v1C[4];
#pragma unroll
    for (int j = 0; j < 4; ++j) {
        uA[j]=0.f; v0B[j]=0.f; v1B[j]=0.f; oB[j]=0.f; p1B[j]=0.f;
        uB[j]=0.f; qB2[j]=0.f; v0C[j]=0.f; v1C[j]=0.f;
    }
    float uA4 = 0.f, uB4 = 0.f;
    float uAa=0.f,uAb=0.f,v0Ba=0.f,v1Ba=0.f,v0Bb=0.f,v1Bb=0.f,oBa=0.f,p1Ba=0.f;
    float oa=0.f,ob=0.f,v0a=0.f,v1a=0.f,v0b=0.f,v1b=0.f;

    for (int t = 0; t < RB + 3; ++t) {
        const int y = r0 - 1 + t;
        const bool act = (y >= 0) && (y < IMG_H);
        const int yc = (y < 0) ? 0 : ((y > IMG_H - 1) ? IMG_H - 1 : y);
        const float* orr = o  + ibase + (size_t)yc * IMG_W;
        const float* vr  = vf + (size_t)yc * IMG_W * 2;

        float4 o4 = *(const float4*)(orr + x0);
        float4 va = *(const float4*)(vr + 2 * x0);
        float4 vb = *(const float4*)(vr + 2 * x0 + 4);
        float oc[4]  = {o4.x, o4.y, o4.z, o4.w};
        float v0c[4] = {va.x, va.z, vb.x, vb.z};
        float v1c[4] = {va.y, va.w, vb.y, vb.w};

        if (edge) {
            float2 op2 = *(const float2*)(orr + pA);
            float4 vp4 = *(const float4*)(vr + 2 * pA);
            if (pair_valid && act) {
                oa = op2.x; ob = op2.y;
                v0a = vp4.x; v1a = vp4.y; v0b = vp4.z; v1b = vp4.w;
            } else {
                oa=0.f; ob=0.f; v0a=0.f; v1a=0.f; v0b=0.f; v1b=0.f;
            }
        }

        // ---- B: u0 = sig2(o) ----
        float ui[4];
#pragma unroll
        for (int j = 0; j < 4; ++j) ui[j] = act ? sig2(oc[j]) : 0.f;
        float ua = (act && pair_valid) ? sig2(oa) : 0.f;
        float ub = (act && pair_valid) ? sig2(ob) : 0.f;

        float sh2 = __shfl_down(ui[0], 1);
        float u4 = is_l63 ? ua : sh2;

        // ---- C: q1 at z (q0 = 0) ----
        const int z = y - 1;
        const bool cz = (z >= qp_lo) && (z <= r0 + RB) && (z < IMG_H);
        float qp[4], p0p[4], p1p[4];
#pragma unroll
        for (int j = 0; j < 4; ++j) {
            float gy = ui[j] - uA[j];
            float gx = ((j < 3) ? uA[j+1] : uA4) - uA[j];
            float qv = cz ? fmaxf(-0.5f*(gy*v1B[j] + gx*v0B[j]), 0.f) : 0.f;
            qp[j] = qv; p0p[j] = v0B[j]*qv; p1p[j] = v1B[j]*qv;
        }
        float gya = ua - uAa, gxa = uAb - uAa;
        float qpa = cz ? fmaxf(-0.5f*(gya*v1Ba + gxa*v0Ba), 0.f) : 0.f;
        float gyb = ub - uAb, gxb = uA[0] - uAb;
        float qpb = cz ? fmaxf(-0.5f*(gyb*v1Bb + gxb*v0Bb), 0.f) : 0.f;
        float p0pa = v0Ba*qpa, p1pa = v1Ba*qpa, p0pb = v0Bb*qpb;

        float sh3 = __shfl_up(p0p[3], 1);
        float p0pleft = is_l0 ? p0pb : sh3;

        // ---- D: u1 at z ----
        const bool dz = (z >= r0) && (z <= r0 + RB) && (z < IMG_H);
        float up[4];
        {
            float Tqp0 = p1p[0] - p1B[0] + p0p[0] - p0pleft;
            up[0] = dz ? sig2(oB[0] - Tqp0) : 0.f;
#pragma unroll
            for (int j = 1; j < 4; ++j) {
                float Tqp = p1p[j] - p1B[j] + p0p[j] - p0p[j-1];
                up[j] = dz ? sig2(oB[j] - Tqp) : 0.f;
            }
        }
        float upa = (dz && pair_valid) ? sig2(oBa - (p1pa - p1Ba + p0pa - p0p[3])) : 0.f;

        float sh4 = __shfl_down(up[0], 1);
        float up4 = is_l63 ? upa : sh4;

        // ---- E: q2 at w -> global ----
        const int w = y - 2;
        if (w >= r0 && w <= r0 + RB - 1) {
            float qq[4];
#pragma unroll
            for (int j = 0; j < 4; ++j) {
                float gy = up[j] - uB[j];
                float gx = ((j < 3) ? uB[j+1] : uB4) - uB[j];
                qq[j] = fmaxf(qB2[j] - 0.5f*(gy*v1C[j] + gx*v0C[j]), 0.f);
            }
            *(float4*)(qout + ibase + (size_t)w * IMG_W + x0) =
                make_float4(qq[0], qq[1], qq[2], qq[3]);
        }

        // ---- rotate ----
#pragma unroll
        for (int j = 0; j < 4; ++j) {
            v0C[j] = v0B[j]; v1C[j] = v1B[j];
            uA[j] = ui[j];
            v0B[j] = v0c[j]; v1B[j] = v1c[j]; oB[j] = oc[j];
            p1B[j] = p1p[j]; uB[j] = up[j]; qB2[j] = qp[j];
        }
        uA4 = u4; uB4 = up4;
        uAa = ua; uAb = ub;
        v0Ba = v0a; v1Ba = v1a; v0Bb = v0b; v1Bb = v1b; oBa = oa; p1Ba = p1pa;
    }
}

// ---------------------------------------------------------------------------
// Final: out = 2*(o - Tq(q10)). One row per block. (Round-2/5/7 verified.)
// ---------------------------------------------------------------------------
__global__ __launch_bounds__(TPB) void k_final(const float* __restrict__ q,
                                               const float* __restrict__ vf,
                                               const float* __restrict__ o,
                                               float* __restrict__ out) {
    __shared__ __align__(16) float sp0[IMG_W + 4];
    const int row = blockIdx.x & (IMG_H - 1);
    const int x0  = threadIdx.x * 4;
    const size_t base = (size_t)blockIdx.x * IMG_W;

    float4 q4 = *(const float4*)(q + base + x0);
    const size_t vbase = ((size_t)row * IMG_W + x0) * 2;
    float4 vfa = *(const float4*)(vf + vbase);
    float4 vfb = *(const float4*)(vf + vbase + 4);

    const float v0[4] = {vfa.x, vfa.z, vfb.x, vfb.z};
    const float v1[4] = {vfa.y, vfa.w, vfb.y, vfb.w};
    const float qc[4] = {q4.x, q4.y, q4.z, q4.w};

    float p0[4], p1[4];
#pragma unroll
    for (int j = 0; j < 4; ++j) {
        p0[j] = v0[j] * qc[j];
        p1[j] = v1[j] * qc[j];
        sp0[x0 + j + 1] = p0[j];
    }
    if (threadIdx.x == 0) sp0[0] = 0.0f;

    float p1m[4];
    if (row > 0) {
        float4 qm  = *(const float4*)(q + base - IMG_W + x0);
        float4 vma = *(const float4*)(vf + vbase - 2 * IMG_W);
        float4 vmb = *(const float4*)(vf + vbase - 2 * IMG_W + 4);
        p1m[0] = qm.x * vma.y; p1m[1] = qm.y * vma.w;
        p1m[2] = qm.z * vmb.y; p1m[3] = qm.w * vmb.w;
    } else {
        p1m[0] = p1m[1] = p1m[2] = p1m[3] = 0.0f;
    }

    float4 o4 = *(const float4*)(o + base + x0);
    const float oc[4] = {o4.x, o4.y, o4.z, o4.w};

    __syncthreads();

    float r[4];
#pragma unroll
    for (int j = 0; j < 4; ++j) {
        float Tq = p1[j] - p1m[j] + p0[j] - sp0[x0 + j];
        r[j] = 2.0f * (oc[j] - Tq);
    }
    *(float4*)(out + base + x0) = make_float4(r[0], r[1], r[2], r[3]);
}

extern "C" void kernel_launch(void* const* d_in, const int* in_sizes, int n_in,
                              void* d_out, int out_size, void* d_ws, size_t ws_size,
                              hipStream_t stream) {
    const float* o  = (const float*)d_in[0];
    const float* vf = (const float*)d_in[1];

    float* bufA = (float*)d_ws;    // q2, q6, q10
    float* bufB = (float*)d_out;   // q4, q8 (overwritten by final output)

    k_init2 <<<NBLK, TPB, 0, stream>>>(o, vf, bufA);         // q2  -> A
    k_fused2<<<NBLK, TPB, 0, stream>>>(bufA, vf, o, bufB);   // q4  -> B
    k_fused2<<<NBLK, TPB, 0, stream>>>(bufB, vf, o, bufA);   // q6  -> A
    k_fused2<<<NBLK, TPB, 0, stream>>>(bufA, vf, o, bufB);   // q8  -> B
    k_fused2<<<NBLK, TPB, 0, stream>>>(bufB, vf, o, bufA);   // q10 -> A
    k_final <<<IMG_B * IMG_H, TPB, 0, stream>>>(bufA, vf, o, (float*)d_out);
}